// Round 9
// baseline (29.669 us; speedup 1.0000x reference)
//
#include <hip/hip_runtime.h>
#include <hip/hip_fp16.h>

typedef _Float16 half8 __attribute__((ext_vector_type(8)));
typedef _Float16 half2v __attribute__((ext_vector_type(2)));
typedef float f32x2 __attribute__((ext_vector_type(2)));
typedef float f32x4 __attribute__((ext_vector_type(4)));

__device__ __forceinline__ float leakyf(float v) { return v >= 0.f ? v : 0.7f * v; }

// Single fused kernel, one dispatch. vs R8:
//  - 512 blocks exactly (2/CU), tiles spread ACROSS blocks (gwave = bid +
//    gridDim*wid) so every CU gets 12-13 tiles (R8: 391 blocks -> half the
//    CUs got 16 tiles, half 8 -> ~2x imbalance).
//  - first tile's tgt row prefetched before weight staging (hides ~900cyc).
//  - readlane + deg1/deg2 scalar loads batched (8-row groups) ahead of the
//    dependent Wc/f loads -> deep memory-level parallelism.
//  - non-temporal stores for outputs, nt loads for single-use f rows.
__global__ __launch_bounds__(512, 4)
void shgnn_fused3(const float* __restrict__ f0, const float* __restrict__ f1,
                  const float* __restrict__ f2, const float* __restrict__ W,
                  const float* __restrict__ b, const float* __restrict__ Wc,
                  const float* __restrict__ bc, const float* __restrict__ Wout,
                  const float* __restrict__ bout,
                  const int* __restrict__ tgt, const int* __restrict__ deg1,
                  const int* __restrict__ deg2,
                  int T, int per_type,
                  float* __restrict__ out_logits, float* __restrict__ out_h)
{
    __shared__ _Float16 sWF[24 * 512];   // 24KB: stacked-W B-frags [ks=0..5][n=0..3]
    __shared__ _Float16 sOF[16 * 512];   // 16KB: Wout B-frags [ks=0..3][n=0..3]
    __shared__ _Float16 sX[8][2048];     // 32KB: per-wave [row=16][ch=128] swizzled
    __shared__ float sB[192];
    __shared__ float sBC[192];
    __shared__ float sBout[64];

    const int tid = threadIdx.x;
    const int lane = tid & 63;
    const int l15 = lane & 15;
    const int lq  = lane >> 4;
    const int wid = tid >> 6;
    char* const sXw = (char*)sX[wid];

    const int ntiles = (T + 15) >> 4;
    const int gwave = blockIdx.x + gridDim.x * wid;   // spread tiles across blocks
    const int nwaves = gridDim.x * 8;

    // ---- prefetch first tile's target ids (hides HBM latency under staging) ----
    int tile = gwave;
    int nnv_pre = 0;
    if (tile < ntiles) {
        int t = tile * 16 + l15; if (t >= T) t = T - 1;
        nnv_pre = __builtin_nontemporal_load(tgt + t);
    }

    // ---- stage weight fragments (coalesced fp32 reads, scattered b16 writes) ----
    for (int i = tid; i < 3 * 64 * 64; i += 512) {         // i = K*64 + col, K=ty*64+k
        const int K = i >> 6, col = i & 63;
        const int ks = K >> 5, j = K & 7;
        const int ln = (((K >> 3) & 3) << 4) | (col & 15);
        const int n = col >> 4;
        sWF[((ks * 4 + n) << 9) + (ln << 3) + j] = (_Float16)W[i];
    }
    for (int i = tid; i < 128 * 64; i += 512) {            // i = k*64 + col
        const int k = i >> 6, col = i & 63;
        const int ks = k >> 5, j = k & 7;
        const int ln = (((k >> 3) & 3) << 4) | (col & 15);
        const int n = col >> 4;
        sOF[((ks * 4 + n) << 9) + (ln << 3) + j] = (_Float16)Wout[i];
    }
    if (tid < 192) sB[tid] = b[tid];
    if (tid < 192) sBC[tid] = bc[tid];
    if (tid < 64)  sBout[tid] = bout[tid];
    __syncthreads();

    const float bc0 = sBC[lane], bc1 = sBC[64 + lane], bc2 = sBC[128 + lane];

    for (; tile < ntiles; tile += nwaves) {
        const int nnv = nnv_pre;
        {   // prefetch next tile's ids (usually no next: single iteration)
            const int tn = tile + nwaves;
            if (tn < ntiles) {
                int t2 = tn * 16 + l15; if (t2 >= T) t2 = T - 1;
                nnv_pre = __builtin_nontemporal_load(tgt + t2);
            }
        }
        const int tyv = (nnv >= 2 * per_type) ? 2 : (nnv >= per_type ? 1 : 0);

        // ---- phase A: per-row coalesced staging, 8-row batches ----
        #pragma unroll
        for (int h = 0; h < 2; ++h) {
            int nr[8], d1r[8], d2r[8];
            #pragma unroll
            for (int r = 0; r < 8; ++r)
                nr[r] = __builtin_amdgcn_readlane(nnv, h * 8 + r);     // SGPR
            #pragma unroll
            for (int r = 0; r < 8; ++r) { d1r[r] = deg1[nr[r]]; d2r[r] = deg2[nr[r]]; }
            #pragma unroll
            for (int r = 0; r < 8; ++r) {
                const int row = h * 8 + r;
                const int tyr = (nr[r] >= 2 * per_type) ? 2 : (nr[r] >= per_type ? 1 : 0);
                const float* fbr = (tyr == 0) ? f0 : ((tyr == 1) ? f1 : f2);
                const float fv = __builtin_nontemporal_load(
                    fbr + (size_t)(nr[r] - tyr * per_type) * 64 + lane);
                const float* wcb = Wc + (size_t)tyr * 12800;
                const float bcv = (tyr == 0) ? bc0 : ((tyr == 1) ? bc1 : bc2);
                const float h2 = leakyf(wcb[d1r[r] * 64 + lane]
                                      + wcb[(100 + d2r[r]) * 64 + lane] + bcv);
                const int swr = (row & 7) << 4;
                *(_Float16*)(sXw + ((row * 256 + lane * 2) ^ swr))       = (_Float16)fv;
                *(_Float16*)(sXw + ((row * 256 + 128 + lane * 2) ^ swr)) = (_Float16)h2;
            }
        }

        // ---- A-frags for h1 from X[.., 0..63] (consumed before overwrite) ----
        const int swl = (l15 & 7) << 4;
        const half8 a0 = *(const half8*)(sXw + ((l15 * 256 + lq * 16) ^ swl));
        const half8 a1 = *(const half8*)(sXw + ((l15 * 256 + 64 + lq * 16) ^ swl));
        const half8 z8 = {(_Float16)0.f, (_Float16)0.f, (_Float16)0.f, (_Float16)0.f,
                          (_Float16)0.f, (_Float16)0.f, (_Float16)0.f, (_Float16)0.f};
        const int k0 = 2 * tyv, k1 = 2 * tyv + 1;     // live k-slices (per-lane)

        int tyr4[4];
        #pragma unroll
        for (int r = 0; r < 4; ++r) tyr4[r] = __shfl(tyv, (lq << 2) + r);

        // ---- h1 = leaky(F~ @ Wstacked + b[ty_row]) : 24 MFMA -> X[.., 0..63] ----
        #pragma unroll
        for (int n = 0; n < 4; ++n) {
            f32x4 acc = {0.f, 0.f, 0.f, 0.f};
            #pragma unroll
            for (int ks = 0; ks < 6; ++ks) {
                const half8 av = (ks == k0) ? a0 : ((ks == k1) ? a1 : z8);
                const half8 wb = *(const half8*)(sWF + ((ks * 4 + n) << 9) + lane * 8);
                acc = __builtin_amdgcn_mfma_f32_16x16x32_f16(av, wb, acc, 0, 0, 0);
            }
            #pragma unroll
            for (int r = 0; r < 4; ++r) {
                const int row = (lq << 2) + r;                // C/D: row=(lane>>4)*4+reg
                const float v = leakyf(acc[r] + sB[tyr4[r] * 64 + n * 16 + l15]);
                const int off = (row * 256 + (n * 16 + l15) * 2) ^ ((row & 7) << 4);
                *(_Float16*)(sXw + off) = (_Float16)v;        // RNE, matches astype(f16)
            }
        }

        // ---- logits = X @ Wout + bout : 16 MFMA ----
        half8 xa[4];
        #pragma unroll
        for (int ks = 0; ks < 4; ++ks)
            xa[ks] = *(const half8*)(sXw + ((l15 * 256 + ks * 64 + lq * 16) ^ swl));

        #pragma unroll
        for (int n = 0; n < 4; ++n) {
            const float bo = (float)(_Float16)sBout[n * 16 + l15];
            f32x4 acc = {bo, bo, bo, bo};
            #pragma unroll
            for (int ks = 0; ks < 4; ++ks) {
                const half8 wf = *(const half8*)(sOF + ((ks * 4 + n) << 9) + lane * 8);
                acc = __builtin_amdgcn_mfma_f32_16x16x32_f16(xa[ks], wf, acc, 0, 0, 0);
            }
            #pragma unroll
            for (int r = 0; r < 4; ++r) {
                int trr = tile * 16 + (lq << 2) + r;
                if (trr >= T) trr = T - 1;
                __builtin_nontemporal_store((float)(_Float16)acc[r],
                    out_logits + (size_t)trr * 64 + n * 16 + l15);
            }
        }

        // ---- out_h: per-row streaming fp32 store (rows consecutive) ----
        #pragma unroll
        for (int r = 0; r < 16; ++r) {
            int tb = tile * 16 + r;
            if (tb >= T) tb = T - 1;
            const half2v hv = *(const half2v*)(sXw + ((r * 256 + lane * 4) ^ ((r & 7) << 4)));
            f32x2 o = {(float)hv.x, (float)hv.y};
            __builtin_nontemporal_store(o, (f32x2*)(out_h + (size_t)tb * 128 + lane * 2));
        }
    }
}

extern "C" void kernel_launch(void* const* d_in, const int* in_sizes, int n_in,
                              void* d_out, int out_size, void* d_ws, size_t ws_size,
                              hipStream_t stream) {
    const float* f0   = (const float*)d_in[0];
    const float* f1   = (const float*)d_in[1];
    const float* f2   = (const float*)d_in[2];
    const float* W    = (const float*)d_in[3];
    const float* b    = (const float*)d_in[4];
    const float* Wc   = (const float*)d_in[5];
    const float* bc   = (const float*)d_in[6];
    const float* Wout = (const float*)d_in[7];
    const float* bout = (const float*)d_in[8];
    const int* deg1   = (const int*)d_in[10];
    const int* deg2   = (const int*)d_in[11];
    const int* tgt    = (const int*)d_in[12];

    const int T = in_sizes[12];
    const int per_type = in_sizes[0] / 64;

    float* out_logits = (float*)d_out;
    float* out_h = out_logits + (size_t)T * 64;

    const int ntiles = (T + 15) / 16;
    int blocks = 512;                    // 2 blocks/CU exactly -> balanced
    if (ntiles < blocks) blocks = ntiles;

    shgnn_fused3<<<dim3(blocks), dim3(512), 0, stream>>>(
        f0, f1, f2, W, b, Wc, bc, Wout, bout,
        tgt, deg1, deg2, T, per_type, out_logits, out_h);
}

// Round 10
// 23.781 us; speedup vs baseline: 1.2476x; 1.2476x over previous
//
#include <hip/hip_runtime.h>
#include <hip/hip_fp16.h>

typedef _Float16 half8 __attribute__((ext_vector_type(8)));
typedef _Float16 half2v __attribute__((ext_vector_type(2)));
typedef float f32x2 __attribute__((ext_vector_type(2)));
typedef float f32x4 __attribute__((ext_vector_type(4)));

__device__ __forceinline__ float leakyf(float v) { return v >= 0.f ? v : 0.7f * v; }

// R8 structure exactly, plus ONE change: balanced chunked tile distribution.
// 512 blocks (2/CU), block b owns a contiguous chunk of ~ntiles/512 tiles,
// wave w processes chunk tile w (stride 8 if chunk > 8). Preserves streaming
// writes within each block; equalizes tiles/CU at 12-14 (R8: 8 vs 16).
__global__ __launch_bounds__(512, 4)
void shgnn_fused4(const float* __restrict__ f0, const float* __restrict__ f1,
                  const float* __restrict__ f2, const float* __restrict__ W,
                  const float* __restrict__ b, const float* __restrict__ Wc,
                  const float* __restrict__ bc, const float* __restrict__ Wout,
                  const float* __restrict__ bout,
                  const int* __restrict__ tgt, const int* __restrict__ deg1,
                  const int* __restrict__ deg2,
                  int T, int per_type,
                  float* __restrict__ out_logits, float* __restrict__ out_h)
{
    __shared__ _Float16 sWF[24 * 512];   // 24KB: stacked-W B-frags [ks=0..5][n=0..3]
    __shared__ _Float16 sOF[16 * 512];   // 16KB: Wout B-frags [ks=0..3][n=0..3]
    __shared__ _Float16 sX[8][2048];     // 32KB: per-wave [row=16][ch=128] swizzled
    __shared__ float sB[192];
    __shared__ float sBC[192];
    __shared__ float sBout[64];

    const int tid = threadIdx.x;

    // ---- stage weight fragments (coalesced fp32 reads, scattered b16 writes) ----
    for (int i = tid; i < 3 * 64 * 64; i += 512) {         // i = K*64 + col, K=ty*64+k
        const int K = i >> 6, col = i & 63;
        const int ks = K >> 5, j = K & 7;
        const int ln = (((K >> 3) & 3) << 4) | (col & 15);
        const int n = col >> 4;
        sWF[((ks * 4 + n) << 9) + (ln << 3) + j] = (_Float16)W[i];
    }
    for (int i = tid; i < 128 * 64; i += 512) {            // i = k*64 + col
        const int k = i >> 6, col = i & 63;
        const int ks = k >> 5, j = k & 7;
        const int ln = (((k >> 3) & 3) << 4) | (col & 15);
        const int n = col >> 4;
        sOF[((ks * 4 + n) << 9) + (ln << 3) + j] = (_Float16)Wout[i];
    }
    if (tid < 192) sB[tid] = b[tid];
    if (tid < 192) sBC[tid] = bc[tid];
    if (tid < 64)  sBout[tid] = bout[tid];
    __syncthreads();

    const int lane = tid & 63;
    const int l15 = lane & 15;
    const int lq  = lane >> 4;
    const int wid = tid >> 6;
    char* const sXw = (char*)sX[wid];

    const int ntiles = (T + 15) >> 4;

    // balanced contiguous chunk per block
    const int nb = gridDim.x;
    const int q = ntiles / nb, rr = ntiles % nb;
    const int cstart = blockIdx.x * q + (blockIdx.x < rr ? blockIdx.x : rr);
    const int cend   = cstart + q + (blockIdx.x < rr ? 1 : 0);

    for (int tile = cstart + wid; tile < cend; tile += 8) {
        int t = tile * 16 + l15;
        if (t >= T) t = T - 1;                        // tail rows duplicate
        const int nnv = tgt[t];                       // coalesced 64B
        const int tyv = (nnv >= 2 * per_type) ? 2 : (nnv >= per_type ? 1 : 0);

        // ---- phase A: per-row coalesced staging (lane = channel) ----
        #pragma unroll
        for (int r = 0; r < 16; ++r) {
            const int nr = __builtin_amdgcn_readlane(nnv, r);          // SGPR
            const int tyr = (nr >= 2 * per_type) ? 2 : (nr >= per_type ? 1 : 0);
            const float* fbr = (tyr == 0) ? f0 : ((tyr == 1) ? f1 : f2);
            const float fv = fbr[(size_t)(nr - tyr * per_type) * 64 + lane];
            const int d1r = deg1[nr];                                  // scalar loads
            const int d2r = deg2[nr];
            const float* wcb = Wc + (size_t)tyr * 12800;
            const float h2 = leakyf(wcb[d1r * 64 + lane] + wcb[(100 + d2r) * 64 + lane]
                                    + sBC[tyr * 64 + lane]);
            const int swr = (r & 7) << 4;
            *(_Float16*)(sXw + ((r * 256 + lane * 2) ^ swr))       = (_Float16)fv;
            *(_Float16*)(sXw + ((r * 256 + 128 + lane * 2) ^ swr)) = (_Float16)h2;
        }

        // ---- A-frags for h1 from X[.., 0..63] (consumed before overwrite) ----
        const int swl = (l15 & 7) << 4;
        const half8 a0 = *(const half8*)(sXw + ((l15 * 256 + lq * 16) ^ swl));
        const half8 a1 = *(const half8*)(sXw + ((l15 * 256 + 64 + lq * 16) ^ swl));
        const half8 z8 = {(_Float16)0.f, (_Float16)0.f, (_Float16)0.f, (_Float16)0.f,
                          (_Float16)0.f, (_Float16)0.f, (_Float16)0.f, (_Float16)0.f};
        const int k0 = 2 * tyv, k1 = 2 * tyv + 1;     // live k-slices (per-lane)

        int tyr4[4];
        #pragma unroll
        for (int r = 0; r < 4; ++r) tyr4[r] = __shfl(tyv, (lq << 2) + r);

        // ---- h1 = leaky(F~ @ Wstacked + b[ty_row]) : 24 MFMA -> X[.., 0..63] ----
        #pragma unroll
        for (int n = 0; n < 4; ++n) {
            f32x4 acc = {0.f, 0.f, 0.f, 0.f};
            #pragma unroll
            for (int ks = 0; ks < 6; ++ks) {
                const half8 av = (ks == k0) ? a0 : ((ks == k1) ? a1 : z8);
                const half8 wb = *(const half8*)(sWF + ((ks * 4 + n) << 9) + lane * 8);
                acc = __builtin_amdgcn_mfma_f32_16x16x32_f16(av, wb, acc, 0, 0, 0);
            }
            #pragma unroll
            for (int r = 0; r < 4; ++r) {
                const int row = (lq << 2) + r;                // C/D: row=(lane>>4)*4+reg
                const float v = leakyf(acc[r] + sB[tyr4[r] * 64 + n * 16 + l15]);
                const int off = (row * 256 + (n * 16 + l15) * 2) ^ ((row & 7) << 4);
                *(_Float16*)(sXw + off) = (_Float16)v;        // RNE, matches astype(f16)
            }
        }

        // ---- logits = X @ Wout + bout : 16 MFMA ----
        half8 xa[4];
        #pragma unroll
        for (int ks = 0; ks < 4; ++ks)
            xa[ks] = *(const half8*)(sXw + ((l15 * 256 + ks * 64 + lq * 16) ^ swl));

        #pragma unroll
        for (int n = 0; n < 4; ++n) {
            const float bo = (float)(_Float16)sBout[n * 16 + l15];
            f32x4 acc = {bo, bo, bo, bo};
            #pragma unroll
            for (int ks = 0; ks < 4; ++ks) {
                const half8 wf = *(const half8*)(sOF + ((ks * 4 + n) << 9) + lane * 8);
                acc = __builtin_amdgcn_mfma_f32_16x16x32_f16(xa[ks], wf, acc, 0, 0, 0);
            }
            #pragma unroll
            for (int r = 0; r < 4; ++r) {
                int trr = tile * 16 + (lq << 2) + r;
                if (trr >= T) trr = T - 1;
                out_logits[(size_t)trr * 64 + n * 16 + l15] = (float)(_Float16)acc[r];
            }
        }

        // ---- out_h: per-row streaming fp32 store (rows consecutive) ----
        #pragma unroll
        for (int r = 0; r < 16; ++r) {
            int tb = tile * 16 + r;
            if (tb >= T) tb = T - 1;
            const half2v hv = *(const half2v*)(sXw + ((r * 256 + lane * 4) ^ ((r & 7) << 4)));
            f32x2 o = {(float)hv.x, (float)hv.y};
            *(f32x2*)(out_h + (size_t)tb * 128 + lane * 2) = o;
        }
    }
}

extern "C" void kernel_launch(void* const* d_in, const int* in_sizes, int n_in,
                              void* d_out, int out_size, void* d_ws, size_t ws_size,
                              hipStream_t stream) {
    const float* f0   = (const float*)d_in[0];
    const float* f1   = (const float*)d_in[1];
    const float* f2   = (const float*)d_in[2];
    const float* W    = (const float*)d_in[3];
    const float* b    = (const float*)d_in[4];
    const float* Wc   = (const float*)d_in[5];
    const float* bc   = (const float*)d_in[6];
    const float* Wout = (const float*)d_in[7];
    const float* bout = (const float*)d_in[8];
    const int* deg1   = (const int*)d_in[10];
    const int* deg2   = (const int*)d_in[11];
    const int* tgt    = (const int*)d_in[12];

    const int T = in_sizes[12];
    const int per_type = in_sizes[0] / 64;

    float* out_logits = (float*)d_out;
    float* out_h = out_logits + (size_t)T * 64;

    const int ntiles = (T + 15) / 16;
    int blocks = 512;                    // 2 blocks/CU exactly -> balanced
    if (ntiles < blocks) blocks = ntiles;

    shgnn_fused4<<<dim3(blocks), dim3(512), 0, stream>>>(
        f0, f1, f2, W, b, Wc, bc, Wout, bout,
        tgt, deg1, deg2, T, per_type, out_logits, out_h);
}

// Round 11
// 20.712 us; speedup vs baseline: 1.4324x; 1.1482x over previous
//
#include <hip/hip_runtime.h>
#include <hip/hip_fp16.h>

typedef _Float16 half8 __attribute__((ext_vector_type(8)));
typedef _Float16 half2v __attribute__((ext_vector_type(2)));
typedef float f32x2 __attribute__((ext_vector_type(2)));
typedef float f32x4 __attribute__((ext_vector_type(4)));

__device__ __forceinline__ float leakyf(float v) { return v >= 0.f ? v : 0.7f * v; }

// R10 structure exactly, plus ONE change: deg1/deg2 fetched as 2 per-lane
// vector gathers at tile start (lane already holds its row's node id), then
// broadcast via v_readlane inside the row loop. Removes 32 scalar loads/tile
// whose shared-lgkmcnt out-of-order returns serialized against the row-loop
// ds_writes.
__global__ __launch_bounds__(512, 4)
void shgnn_fused5(const float* __restrict__ f0, const float* __restrict__ f1,
                  const float* __restrict__ f2, const float* __restrict__ W,
                  const float* __restrict__ b, const float* __restrict__ Wc,
                  const float* __restrict__ bc, const float* __restrict__ Wout,
                  const float* __restrict__ bout,
                  const int* __restrict__ tgt, const int* __restrict__ deg1,
                  const int* __restrict__ deg2,
                  int T, int per_type,
                  float* __restrict__ out_logits, float* __restrict__ out_h)
{
    __shared__ _Float16 sWF[24 * 512];   // 24KB: stacked-W B-frags [ks=0..5][n=0..3]
    __shared__ _Float16 sOF[16 * 512];   // 16KB: Wout B-frags [ks=0..3][n=0..3]
    __shared__ _Float16 sX[8][2048];     // 32KB: per-wave [row=16][ch=128] swizzled
    __shared__ float sB[192];
    __shared__ float sBC[192];
    __shared__ float sBout[64];

    const int tid = threadIdx.x;

    // ---- stage weight fragments (coalesced fp32 reads, scattered b16 writes) ----
    for (int i = tid; i < 3 * 64 * 64; i += 512) {         // i = K*64 + col, K=ty*64+k
        const int K = i >> 6, col = i & 63;
        const int ks = K >> 5, j = K & 7;
        const int ln = (((K >> 3) & 3) << 4) | (col & 15);
        const int n = col >> 4;
        sWF[((ks * 4 + n) << 9) + (ln << 3) + j] = (_Float16)W[i];
    }
    for (int i = tid; i < 128 * 64; i += 512) {            // i = k*64 + col
        const int k = i >> 6, col = i & 63;
        const int ks = k >> 5, j = k & 7;
        const int ln = (((k >> 3) & 3) << 4) | (col & 15);
        const int n = col >> 4;
        sOF[((ks * 4 + n) << 9) + (ln << 3) + j] = (_Float16)Wout[i];
    }
    if (tid < 192) sB[tid] = b[tid];
    if (tid < 192) sBC[tid] = bc[tid];
    if (tid < 64)  sBout[tid] = bout[tid];
    __syncthreads();

    const int lane = tid & 63;
    const int l15 = lane & 15;
    const int lq  = lane >> 4;
    const int wid = tid >> 6;
    char* const sXw = (char*)sX[wid];

    const int ntiles = (T + 15) >> 4;

    // balanced contiguous chunk per block
    const int nb = gridDim.x;
    const int q = ntiles / nb, rr = ntiles % nb;
    const int cstart = blockIdx.x * q + (blockIdx.x < rr ? blockIdx.x : rr);
    const int cend   = cstart + q + (blockIdx.x < rr ? 1 : 0);

    for (int tile = cstart + wid; tile < cend; tile += 8) {
        int t = tile * 16 + l15;
        if (t >= T) t = T - 1;                        // tail rows duplicate
        const int nnv = tgt[t];                       // coalesced 64B
        const int tyv = (nnv >= 2 * per_type) ? 2 : (nnv >= per_type ? 1 : 0);

        // per-lane deg gathers (one instruction each; rows' values in lanes 0..15)
        const int d1v = deg1[nnv];
        const int d2v = deg2[nnv];

        // ---- phase A: per-row coalesced staging (lane = channel) ----
        #pragma unroll
        for (int r = 0; r < 16; ++r) {
            const int nr  = __builtin_amdgcn_readlane(nnv, r);         // SGPR
            const int d1r = __builtin_amdgcn_readlane(d1v, r);
            const int d2r = __builtin_amdgcn_readlane(d2v, r);
            const int tyr = (nr >= 2 * per_type) ? 2 : (nr >= per_type ? 1 : 0);
            const float* fbr = (tyr == 0) ? f0 : ((tyr == 1) ? f1 : f2);
            const float fv = fbr[(size_t)(nr - tyr * per_type) * 64 + lane];
            const float* wcb = Wc + (size_t)tyr * 12800;
            const float h2 = leakyf(wcb[d1r * 64 + lane] + wcb[(100 + d2r) * 64 + lane]
                                    + sBC[tyr * 64 + lane]);
            const int swr = (r & 7) << 4;
            *(_Float16*)(sXw + ((r * 256 + lane * 2) ^ swr))       = (_Float16)fv;
            *(_Float16*)(sXw + ((r * 256 + 128 + lane * 2) ^ swr)) = (_Float16)h2;
        }

        // ---- A-frags for h1 from X[.., 0..63] (consumed before overwrite) ----
        const int swl = (l15 & 7) << 4;
        const half8 a0 = *(const half8*)(sXw + ((l15 * 256 + lq * 16) ^ swl));
        const half8 a1 = *(const half8*)(sXw + ((l15 * 256 + 64 + lq * 16) ^ swl));
        const half8 z8 = {(_Float16)0.f, (_Float16)0.f, (_Float16)0.f, (_Float16)0.f,
                          (_Float16)0.f, (_Float16)0.f, (_Float16)0.f, (_Float16)0.f};
        const int k0 = 2 * tyv, k1 = 2 * tyv + 1;     // live k-slices (per-lane)

        int tyr4[4];
        #pragma unroll
        for (int r = 0; r < 4; ++r) tyr4[r] = __shfl(tyv, (lq << 2) + r);

        // ---- h1 = leaky(F~ @ Wstacked + b[ty_row]) : 24 MFMA -> X[.., 0..63] ----
        #pragma unroll
        for (int n = 0; n < 4; ++n) {
            f32x4 acc = {0.f, 0.f, 0.f, 0.f};
            #pragma unroll
            for (int ks = 0; ks < 6; ++ks) {
                const half8 av = (ks == k0) ? a0 : ((ks == k1) ? a1 : z8);
                const half8 wb = *(const half8*)(sWF + ((ks * 4 + n) << 9) + lane * 8);
                acc = __builtin_amdgcn_mfma_f32_16x16x32_f16(av, wb, acc, 0, 0, 0);
            }
            #pragma unroll
            for (int r = 0; r < 4; ++r) {
                const int row = (lq << 2) + r;                // C/D: row=(lane>>4)*4+reg
                const float v = leakyf(acc[r] + sB[tyr4[r] * 64 + n * 16 + l15]);
                const int off = (row * 256 + (n * 16 + l15) * 2) ^ ((row & 7) << 4);
                *(_Float16*)(sXw + off) = (_Float16)v;        // RNE, matches astype(f16)
            }
        }

        // ---- logits = X @ Wout + bout : 16 MFMA ----
        half8 xa[4];
        #pragma unroll
        for (int ks = 0; ks < 4; ++ks)
            xa[ks] = *(const half8*)(sXw + ((l15 * 256 + ks * 64 + lq * 16) ^ swl));

        #pragma unroll
        for (int n = 0; n < 4; ++n) {
            const float bo = (float)(_Float16)sBout[n * 16 + l15];
            f32x4 acc = {bo, bo, bo, bo};
            #pragma unroll
            for (int ks = 0; ks < 4; ++ks) {
                const half8 wf = *(const half8*)(sOF + ((ks * 4 + n) << 9) + lane * 8);
                acc = __builtin_amdgcn_mfma_f32_16x16x32_f16(xa[ks], wf, acc, 0, 0, 0);
            }
            #pragma unroll
            for (int r = 0; r < 4; ++r) {
                int trr = tile * 16 + (lq << 2) + r;
                if (trr >= T) trr = T - 1;
                out_logits[(size_t)trr * 64 + n * 16 + l15] = (float)(_Float16)acc[r];
            }
        }

        // ---- out_h: per-row streaming fp32 store (rows consecutive) ----
        #pragma unroll
        for (int r = 0; r < 16; ++r) {
            int tb = tile * 16 + r;
            if (tb >= T) tb = T - 1;
            const half2v hv = *(const half2v*)(sXw + ((r * 256 + lane * 4) ^ ((r & 7) << 4)));
            f32x2 o = {(float)hv.x, (float)hv.y};
            *(f32x2*)(out_h + (size_t)tb * 128 + lane * 2) = o;
        }
    }
}

extern "C" void kernel_launch(void* const* d_in, const int* in_sizes, int n_in,
                              void* d_out, int out_size, void* d_ws, size_t ws_size,
                              hipStream_t stream) {
    const float* f0   = (const float*)d_in[0];
    const float* f1   = (const float*)d_in[1];
    const float* f2   = (const float*)d_in[2];
    const float* W    = (const float*)d_in[3];
    const float* b    = (const float*)d_in[4];
    const float* Wc   = (const float*)d_in[5];
    const float* bc   = (const float*)d_in[6];
    const float* Wout = (const float*)d_in[7];
    const float* bout = (const float*)d_in[8];
    const int* deg1   = (const int*)d_in[10];
    const int* deg2   = (const int*)d_in[11];
    const int* tgt    = (const int*)d_in[12];

    const int T = in_sizes[12];
    const int per_type = in_sizes[0] / 64;

    float* out_logits = (float*)d_out;
    float* out_h = out_logits + (size_t)T * 64;

    const int ntiles = (T + 15) / 16;
    int blocks = 512;                    // 2 blocks/CU exactly -> balanced
    if (ntiles < blocks) blocks = ntiles;

    shgnn_fused5<<<dim3(blocks), dim3(512), 0, stream>>>(
        f0, f1, f2, W, b, Wc, bc, Wout, bout,
        tgt, deg1, deg2, T, per_type, out_logits, out_h);
}